// Round 1
// baseline (182.658 us; speedup 1.0000x reference)
//
#include <hip/hip_runtime.h>
#include <hip/hip_bf16.h>

typedef __attribute__((ext_vector_type(8))) short short8;
typedef __attribute__((ext_vector_type(4))) float f32x4;

#define NSEQ 128
#define NRES 256
#define CM   256
#define CC   32
#define CZ   128

// ws layout: A' [8192][128] bf16 (2MB) | B' [8192][128] bf16 (2MB) | WoutT [128][1024] bf16 (256KB)
#define WS_A 0
#define WS_B (8192 * 128 * 2)
#define WS_WT (2 * 8192 * 128 * 2)

// ---------------- Kernel 0: Wout (1024,128) f32 -> WoutT (128,1024) bf16 ----------------
__global__ __launch_bounds__(256) void k_wout(const float* __restrict__ Wout,
                                              __hip_bfloat16* __restrict__ WoutT) {
    int idx = blockIdx.x * 256 + threadIdx.x;     // 131072 total
    int z = idx >> 10, ck = idx & 1023;
    WoutT[idx] = __float2bfloat16(Wout[ck * CZ + z]);
}

// ---------------- Kernel 1: LayerNorm + dual projection ----------------
// grid: 2048 blocks x 256 thr; each wave handles 4 rows (s,i) of m.
// Writes Ap[(i*32+c)*128 + s], Bp[(j*32+k)*128 + s] as bf16.
__global__ __launch_bounds__(256) void k_lnproj(const float* __restrict__ mm,
                                                const float* __restrict__ gamma,
                                                const float* __restrict__ beta,
                                                const float* __restrict__ W1,
                                                const float* __restrict__ b1,
                                                const float* __restrict__ W2,
                                                const float* __restrict__ b2,
                                                __hip_bfloat16* __restrict__ Ap,
                                                __hip_bfloat16* __restrict__ Bp) {
    __shared__ float mn[4][4][256];   // [wave][rr][d] = 16KB
    const int lane = threadIdx.x & 63;
    const int wid  = threadIdx.x >> 6;
    const int base = (blockIdx.x * 4 + wid) * 4;   // first of 4 rows

    float4 g4  = *(const float4*)&gamma[lane * 4];
    float4 be4 = *(const float4*)&beta[lane * 4];

    #pragma unroll
    for (int rr = 0; rr < 4; rr++) {
        int row = base + rr;
        float4 x = *(const float4*)&mm[(size_t)row * 256 + lane * 4];
        float s  = x.x + x.y + x.z + x.w;
        float ss = x.x * x.x + x.y * x.y + x.z * x.z + x.w * x.w;
        #pragma unroll
        for (int off = 32; off; off >>= 1) {
            s  += __shfl_xor(s, off);
            ss += __shfl_xor(ss, off);
        }
        float mu  = s * (1.f / 256.f);
        float var = ss * (1.f / 256.f) - mu * mu;
        float rs  = rsqrtf(var + 1e-5f);
        float4 y;
        y.x = (x.x - mu) * rs * g4.x + be4.x;
        y.y = (x.y - mu) * rs * g4.y + be4.y;
        y.z = (x.z - mu) * rs * g4.z + be4.z;
        y.w = (x.w - mu) * rs * g4.w + be4.w;
        *(float4*)&mn[wid][rr][lane * 4] = y;
    }
    __syncthreads();

    const int cc  = lane & 31;
    const int sel = lane >> 5;
    const float* W = sel ? W2 : W1;
    float bias = sel ? b2[cc] : b1[cc];
    float a0 = bias, a1 = bias, a2 = bias, a3 = bias;
    #pragma unroll 8
    for (int d = 0; d < 256; d++) {
        float w = W[d * 32 + cc];
        a0 += mn[wid][0][d] * w;
        a1 += mn[wid][1][d] * w;
        a2 += mn[wid][2][d] * w;
        a3 += mn[wid][3][d] * w;
    }
    __hip_bfloat16* Out = sel ? Bp : Ap;
    float acc[4] = {a0, a1, a2, a3};
    #pragma unroll
    for (int rr = 0; rr < 4; rr++) {
        int row = base + rr;
        int s_ = row >> 8;          // row = s*256 + i
        int i_ = row & 255;
        Out[(i_ * 32 + cc) * 128 + s_] = __float2bfloat16(acc[rr]);
    }
}

// ---------------- Kernel 2: O = A'.B'^T (K=128) fused with Z = P @ WoutT + bout, /128 ----
// grid 4096 (64x64 tiles of 4 i's x 4 j's), 256 threads (4 waves, 2x2 of 64x64).
__global__ __launch_bounds__(256) void k_gemm(const __hip_bfloat16* __restrict__ Apb,
                                              const __hip_bfloat16* __restrict__ Bpb,
                                              const __hip_bfloat16* __restrict__ WoutT,
                                              const float* __restrict__ bout,
                                              float* __restrict__ out) {
    __shared__ __align__(16) short smem[32768];   // 64KB: sA [0,16384) sB [16384,32768)
    short* sA = smem;
    short* sB = smem + 16384;
    short* sP = smem;                              // reuse sA region after barrier

    const int t = threadIdx.x, lane = t & 63, wid = t >> 6;
    const int wr = wid >> 1, wc = wid & 1;
    const int br = blockIdx.x >> 6, bc = blockIdx.x & 63;

    const short* gA = (const short*)Apb + br * 128 * 128;
    const short* gB = (const short*)Bpb + bc * 128 * 128;

    // stage A,B tiles (128 rows x 128 s, bf16) with XOR swizzle on 16B granules
    #pragma unroll
    for (int it = 0; it < 8; it++) {
        int chunk = t + it * 256;          // 0..2047
        int row = chunk >> 4, sc = chunk & 15;
        int swsc = sc ^ (row & 7);
        short8 va = *(const short8*)&gA[row * 128 + sc * 8];
        short8 vb = *(const short8*)&gB[row * 128 + sc * 8];
        *(short8*)&sA[row * 128 + swsc * 8] = va;
        *(short8*)&sB[row * 128 + swsc * 8] = vb;
    }
    __syncthreads();

    f32x4 acc[4][4];
    #pragma unroll
    for (int mf = 0; mf < 4; mf++)
        #pragma unroll
        for (int nf = 0; nf < 4; nf++)
            acc[mf][nf] = (f32x4){0.f, 0.f, 0.f, 0.f};

    #pragma unroll
    for (int ks = 0; ks < 4; ks++) {
        const int kb = ks * 32 + (lane >> 4) * 8;   // element offset along K(=s)
        short8 af[4], bf[4];
        #pragma unroll
        for (int mf = 0; mf < 4; mf++) {
            int row = wr * 64 + mf * 16 + (lane & 15);
            af[mf] = *(const short8*)&sA[row * 128 + (kb ^ ((row & 7) << 3))];
        }
        #pragma unroll
        for (int nf = 0; nf < 4; nf++) {
            int rowb = wc * 64 + nf * 16 + (lane & 15);
            bf[nf] = *(const short8*)&sB[rowb * 128 + (kb ^ ((rowb & 7) << 3))];
        }
        #pragma unroll
        for (int mf = 0; mf < 4; mf++)
            #pragma unroll
            for (int nf = 0; nf < 4; nf++)
                acc[mf][nf] = __builtin_amdgcn_mfma_f32_16x16x32_bf16(af[mf], bf[nf], acc[mf][nf], 0, 0, 0);
    }
    __syncthreads();

    // repack O tile -> P[16 pairs][1024 ck] bf16 (swizzled), overlapping sA
    #pragma unroll
    for (int mf = 0; mf < 4; mf++) {
        #pragma unroll
        for (int nf = 0; nf < 4; nf++) {
            #pragma unroll
            for (int reg = 0; reg < 4; reg++) {
                int rowm = wr * 64 + mf * 16 + (lane >> 4) * 4 + reg;  // (ii,c)
                int coln = wc * 64 + nf * 16 + (lane & 15);            // (jj,k)
                int p  = (rowm >> 5) * 4 + (coln >> 5);
                int ck = (rowm & 31) * 32 + (coln & 31);
                ((__hip_bfloat16*)sP)[p * 1024 + (ck ^ ((p & 7) << 3))] =
                    __float2bfloat16(acc[mf][nf][reg]);
            }
        }
    }
    __syncthreads();

    // epilogue GEMM: Z[16][128] = P @ WoutT^T ; wave wid covers z-cols [wid*32, wid*32+32)
    f32x4 acc2[2];
    acc2[0] = (f32x4){0.f, 0.f, 0.f, 0.f};
    acc2[1] = (f32x4){0.f, 0.f, 0.f, 0.f};
    const short* wt = (const short*)WoutT;
    #pragma unroll 4
    for (int ks = 0; ks < 32; ks++) {
        int ckb = ks * 32 + (lane >> 4) * 8;
        int p = lane & 15;
        short8 pf = *(const short8*)&sP[p * 1024 + (ckb ^ ((p & 7) << 3))];
        #pragma unroll
        for (int nf = 0; nf < 2; nf++) {
            int z = wid * 32 + nf * 16 + (lane & 15);
            short8 wf = *(const short8*)&wt[z * 1024 + ckb];
            acc2[nf] = __builtin_amdgcn_mfma_f32_16x16x32_bf16(pf, wf, acc2[nf], 0, 0, 0);
        }
    }

    #pragma unroll
    for (int nf = 0; nf < 2; nf++) {
        int z = wid * 32 + nf * 16 + (lane & 15);
        float bz = bout[z];
        #pragma unroll
        for (int reg = 0; reg < 4; reg++) {
            int p = (lane >> 4) * 4 + reg;
            int ig = br * 4 + (p >> 2), jg = bc * 4 + (p & 3);
            out[((size_t)(ig * 256 + jg)) * 128 + z] = (acc2[nf][reg] + bz) * (1.f / 128.f);
        }
    }
}

extern "C" void kernel_launch(void* const* d_in, const int* in_sizes, int n_in,
                              void* d_out, int out_size, void* d_ws, size_t ws_size,
                              hipStream_t stream) {
    const float* mm    = (const float*)d_in[0];
    const float* gamma = (const float*)d_in[1];
    const float* beta  = (const float*)d_in[2];
    const float* W1    = (const float*)d_in[3];
    const float* b1    = (const float*)d_in[4];
    const float* W2    = (const float*)d_in[5];
    const float* b2    = (const float*)d_in[6];
    const float* Wout  = (const float*)d_in[7];
    const float* bout  = (const float*)d_in[8];

    __hip_bfloat16* Ap    = (__hip_bfloat16*)((char*)d_ws + WS_A);
    __hip_bfloat16* Bp    = (__hip_bfloat16*)((char*)d_ws + WS_B);
    __hip_bfloat16* WoutT = (__hip_bfloat16*)((char*)d_ws + WS_WT);
    float* out = (float*)d_out;

    hipLaunchKernelGGL(k_wout, dim3(512), dim3(256), 0, stream, Wout, WoutT);
    hipLaunchKernelGGL(k_lnproj, dim3(2048), dim3(256), 0, stream,
                       mm, gamma, beta, W1, b1, W2, b2, Ap, Bp);
    hipLaunchKernelGGL(k_gemm, dim3(4096), dim3(256), 0, stream,
                       Ap, Bp, WoutT, bout, out);
}

// Round 2
// 169.697 us; speedup vs baseline: 1.0764x; 1.0764x over previous
//
#include <hip/hip_runtime.h>
#include <hip/hip_bf16.h>

typedef __attribute__((ext_vector_type(8))) short short8;
typedef __attribute__((ext_vector_type(4))) short short4v;
typedef __attribute__((ext_vector_type(4))) float f32x4;

#define NSEQ 128
#define NRES 256
#define CM   256

// ws layout: A' [8192][128] bf16 (2MB) | B' [8192][128] bf16 (2MB) |
//            WoutT [128][1024] bf16 (256KB) | W12t [64][256] f32 (64KB)
#define WS_A   0
#define WS_B   (8192 * 128 * 2)
#define WS_WT  (2 * 8192 * 128 * 2)
#define WS_W12 (WS_WT + 128 * 1024 * 2)

static __device__ __forceinline__ short f2bf(float x) {
    __hip_bfloat16 h = __float2bfloat16(x);
    return *reinterpret_cast<short*>(&h);
}

// ---------------- Kernel 0: transpose Wout -> bf16 [z][ck], W1/W2 -> f32 [64][256] ----------------
__global__ __launch_bounds__(256) void k_prep(const float* __restrict__ Wout,
                                              const float* __restrict__ W1,
                                              const float* __restrict__ W2,
                                              __hip_bfloat16* __restrict__ WoutT,
                                              float* __restrict__ W12t) {
    int idx = blockIdx.x * 256 + threadIdx.x;
    if (blockIdx.x < 512) {
        int z = idx >> 10, ck = idx & 1023;
        WoutT[idx] = __float2bfloat16(Wout[ck * 128 + z]);
    } else {
        idx -= 512 * 256;                  // 0..16383
        int c = idx >> 8, d = idx & 255;
        W12t[idx] = (c < 32) ? W1[d * 32 + c] : W2[d * 32 + (c - 32)];
    }
}

// ---------------- Kernel 1: LayerNorm + dual projection ----------------
// group g = blockIdx*4+wid handles rows (sb+rr)*256 + i  (4 consecutive s, fixed i)
// so each lane's 4 outputs are s-consecutive -> one 8B store.
__global__ __launch_bounds__(256) void k_lnproj(const float* __restrict__ mm,
                                                const float* __restrict__ gamma,
                                                const float* __restrict__ beta,
                                                const float* __restrict__ b1,
                                                const float* __restrict__ b2,
                                                const float* __restrict__ W12t,
                                                __hip_bfloat16* __restrict__ Ap,
                                                __hip_bfloat16* __restrict__ Bp) {
    __shared__ float mn[4][4][256];   // [wave][rr][d] = 16KB
    const int lane = threadIdx.x & 63;
    const int wid  = threadIdx.x >> 6;
    const int g    = blockIdx.x * 4 + wid;   // 0..8191
    const int i_   = g & 255;
    const int sb   = (g >> 8) * 4;           // 0,4,...,124

    float4 g4  = *(const float4*)&gamma[lane * 4];
    float4 be4 = *(const float4*)&beta[lane * 4];

    #pragma unroll
    for (int rr = 0; rr < 4; rr++) {
        size_t row = (size_t)(sb + rr) * 256 + i_;
        float4 x = *(const float4*)&mm[row * 256 + lane * 4];
        float s  = x.x + x.y + x.z + x.w;
        float ss = x.x * x.x + x.y * x.y + x.z * x.z + x.w * x.w;
        #pragma unroll
        for (int off = 32; off; off >>= 1) {
            s  += __shfl_xor(s, off);
            ss += __shfl_xor(ss, off);
        }
        float mu  = s * (1.f / 256.f);
        float var = ss * (1.f / 256.f) - mu * mu;
        float rs  = rsqrtf(var + 1e-5f);
        float4 y;
        y.x = (x.x - mu) * rs * g4.x + be4.x;
        y.y = (x.y - mu) * rs * g4.y + be4.y;
        y.z = (x.z - mu) * rs * g4.z + be4.z;
        y.w = (x.w - mu) * rs * g4.w + be4.w;
        *(float4*)&mn[wid][rr][lane * 4] = y;
    }
    __syncthreads();

    // projection: lane = sel*32+cc picks row of W12t; all 64 lanes busy
    const int cc  = lane & 31;
    const int sel = lane >> 5;
    const float* wrow = W12t + lane * 256;
    float bias = sel ? b2[cc] : b1[cc];
    float a0 = bias, a1 = bias, a2 = bias, a3 = bias;
    #pragma unroll 4
    for (int d = 0; d < 256; d += 4) {
        float4 w  = *(const float4*)&wrow[d];
        float4 m0 = *(const float4*)&mn[wid][0][d];
        float4 m1 = *(const float4*)&mn[wid][1][d];
        float4 m2 = *(const float4*)&mn[wid][2][d];
        float4 m3 = *(const float4*)&mn[wid][3][d];
        a0 += m0.x * w.x + m0.y * w.y + m0.z * w.z + m0.w * w.w;
        a1 += m1.x * w.x + m1.y * w.y + m1.z * w.z + m1.w * w.w;
        a2 += m2.x * w.x + m2.y * w.y + m2.z * w.z + m2.w * w.w;
        a3 += m3.x * w.x + m3.y * w.y + m3.z * w.z + m3.w * w.w;
    }
    __hip_bfloat16* Out = sel ? Bp : Ap;
    short4v v;
    v.x = f2bf(a0); v.y = f2bf(a1); v.z = f2bf(a2); v.w = f2bf(a3);
    *(short4v*)&Out[(i_ * 32 + cc) * 128 + sb] = v;
}

// ---------------- Kernel 2: O = A'.B'^T (K=128) fused with Z = P @ WoutT^T + bout, /128 ----
// grid 1024 (32x32 tiles of 8 i x 8 j), 512 threads (8 waves: 2M x 4N of 128x64).
// A/B fragments loaded DIRECT from global (L2-resident) - no staging, no barriers in main loop.
// LDS holds only P [64][1024] bf16 (128KB, XOR-swizzled at 16B granules).
extern __shared__ char dsmem[];

__global__ __launch_bounds__(512, 2) void k_gemm2(const __hip_bfloat16* __restrict__ Apb,
                                                  const __hip_bfloat16* __restrict__ Bpb,
                                                  const __hip_bfloat16* __restrict__ WoutT,
                                                  const float* __restrict__ bout,
                                                  float* __restrict__ out) {
    short* sP = (short*)dsmem;   // [64][1024] bf16, element swz: ck ^ ((p&7)<<3)

    const int t = threadIdx.x, lane = t & 63, wid = t >> 6;
    const int wr = wid >> 2, wc = wid & 3;
    const int br = blockIdx.x >> 5, bc = blockIdx.x & 31;

    const short* gA = (const short*)Apb + (size_t)br * 256 * 128;
    const short* gB = (const short*)Bpb + (size_t)bc * 256 * 128;

    f32x4 acc[8][4];
    #pragma unroll
    for (int mf = 0; mf < 8; mf++)
        #pragma unroll
        for (int nf = 0; nf < 4; nf++)
            acc[mf][nf] = (f32x4){0.f, 0.f, 0.f, 0.f};

    #pragma unroll
    for (int ks = 0; ks < 4; ks++) {
        const int kb = ks * 32 + (lane >> 4) * 8;
        short8 af[8], bf[4];
        #pragma unroll
        for (int mf = 0; mf < 8; mf++) {
            int row = wr * 128 + mf * 16 + (lane & 15);
            af[mf] = *(const short8*)&gA[row * 128 + kb];
        }
        #pragma unroll
        for (int nf = 0; nf < 4; nf++) {
            int row = wc * 64 + nf * 16 + (lane & 15);
            bf[nf] = *(const short8*)&gB[row * 128 + kb];
        }
        #pragma unroll
        for (int mf = 0; mf < 8; mf++)
            #pragma unroll
            for (int nf = 0; nf < 4; nf++)
                acc[mf][nf] = __builtin_amdgcn_mfma_f32_16x16x32_bf16(af[mf], bf[nf], acc[mf][nf], 0, 0, 0);
    }

    // repack O tile -> P[64 pairs][1024 ck] bf16 in LDS
    #pragma unroll
    for (int mf = 0; mf < 8; mf++) {
        #pragma unroll
        for (int nf = 0; nf < 4; nf++) {
            const int p = (wr * 4 + (mf >> 1)) * 8 + wc * 2 + (nf >> 1);
            #pragma unroll
            for (int reg = 0; reg < 4; reg++) {
                int ck = ((mf & 1) * 16 + (lane >> 4) * 4 + reg) * 32 + (nf & 1) * 16 + (lane & 15);
                sP[p * 1024 + (ck ^ ((p & 7) << 3))] = f2bf(acc[mf][nf][reg]);
            }
        }
    }
    __syncthreads();

    // epilogue GEMM: Z[64][128] = P @ WoutT^T ; wave wid covers z in [wid*16, wid*16+16)
    f32x4 acc2[4];
    #pragma unroll
    for (int mf = 0; mf < 4; mf++) acc2[mf] = (f32x4){0.f, 0.f, 0.f, 0.f};

    const short* wt = (const short*)WoutT;
    const int z = wid * 16 + (lane & 15);
    #pragma unroll 4
    for (int ks = 0; ks < 32; ks++) {
        int gblk = ks * 32 + (lane >> 4) * 8;
        short8 wf = *(const short8*)&wt[z * 1024 + gblk];
        #pragma unroll
        for (int mf = 0; mf < 4; mf++) {
            int p = mf * 16 + (lane & 15);
            short8 pf = *(const short8*)&sP[p * 1024 + (gblk ^ ((p & 7) << 3))];
            acc2[mf] = __builtin_amdgcn_mfma_f32_16x16x32_bf16(pf, wf, acc2[mf], 0, 0, 0);
        }
    }

    float bz = bout[z];
    #pragma unroll
    for (int mf = 0; mf < 4; mf++) {
        #pragma unroll
        for (int reg = 0; reg < 4; reg++) {
            int p = mf * 16 + (lane >> 4) * 4 + reg;
            int ig = br * 8 + (p >> 3), jg = bc * 8 + (p & 7);
            out[((size_t)(ig * 256 + jg)) * 128 + z] = (acc2[mf][reg] + bz) * (1.f / 128.f);
        }
    }
}

extern "C" void kernel_launch(void* const* d_in, const int* in_sizes, int n_in,
                              void* d_out, int out_size, void* d_ws, size_t ws_size,
                              hipStream_t stream) {
    const float* mm    = (const float*)d_in[0];
    const float* gamma = (const float*)d_in[1];
    const float* beta  = (const float*)d_in[2];
    const float* W1    = (const float*)d_in[3];
    const float* b1    = (const float*)d_in[4];
    const float* W2    = (const float*)d_in[5];
    const float* b2    = (const float*)d_in[6];
    const float* Wout  = (const float*)d_in[7];
    const float* bout  = (const float*)d_in[8];

    __hip_bfloat16* Ap    = (__hip_bfloat16*)((char*)d_ws + WS_A);
    __hip_bfloat16* Bp    = (__hip_bfloat16*)((char*)d_ws + WS_B);
    __hip_bfloat16* WoutT = (__hip_bfloat16*)((char*)d_ws + WS_WT);
    float*          W12t  = (float*)((char*)d_ws + WS_W12);
    float* out = (float*)d_out;

    static int lds_set = 0;
    (void)hipFuncSetAttribute(reinterpret_cast<const void*>(k_gemm2),
                              hipFuncAttributeMaxDynamicSharedMemorySize, 131072);

    hipLaunchKernelGGL(k_prep, dim3(576), dim3(256), 0, stream, Wout, W1, W2, WoutT, W12t);
    hipLaunchKernelGGL(k_lnproj, dim3(2048), dim3(256), 0, stream,
                       mm, gamma, beta, b1, b2, W12t, Ap, Bp);
    hipLaunchKernelGGL(k_gemm2, dim3(1024), dim3(512), 131072, stream,
                       Ap, Bp, WoutT, bout, out);
}

// Round 3
// 142.140 us; speedup vs baseline: 1.2851x; 1.1939x over previous
//
#include <hip/hip_runtime.h>
#include <hip/hip_bf16.h>

typedef __attribute__((ext_vector_type(8))) short short8;
typedef __attribute__((ext_vector_type(4))) short short4v;
typedef __attribute__((ext_vector_type(4))) float f32x4;

// ws: A' [8192][128] bf16 (2MB) | B' [8192][128] bf16 (2MB) |
//     WoutT [128][1024] bf16 (256KB) | W12bf [64][256] bf16 (32KB)
#define WS_A   0
#define WS_B   (8192 * 128 * 2)
#define WS_WT  (2 * 8192 * 128 * 2)
#define WS_W12 (WS_WT + 128 * 1024 * 2)

static __device__ __forceinline__ short f2bf(float x) {
    __hip_bfloat16 h = __float2bfloat16(x);
    return *reinterpret_cast<short*>(&h);
}

// ---------------- Kernel 0: Wout -> bf16 [z][ck]; W1|W2 -> bf16 [64 c][256 d] ----------------
__global__ __launch_bounds__(256) void k_prep(const float* __restrict__ Wout,
                                              const float* __restrict__ W1,
                                              const float* __restrict__ W2,
                                              __hip_bfloat16* __restrict__ WoutT,
                                              __hip_bfloat16* __restrict__ W12bf) {
    int idx = blockIdx.x * 256 + threadIdx.x;
    if (blockIdx.x < 512) {
        int z = idx >> 10, ck = idx & 1023;
        WoutT[idx] = __float2bfloat16(Wout[ck * 128 + z]);
    } else {
        idx -= 512 * 256;                  // 0..16383
        int c = idx >> 8, d = idx & 255;
        W12bf[idx] = __float2bfloat16(c < 32 ? W1[d * 32 + c] : W2[d * 32 + (c - 32)]);
    }
}

// ---------------- Kernel 1: LayerNorm + dual projection via MFMA ----------------
// wave gw handles rows (i = gw&255, s = (gw>>8)*16 .. +15). LN -> bf16 LDS (swizzled)
// -> A-frags; B = W12bf[64][256] global (L1/L2-hot). Bias in acc init.
__global__ __launch_bounds__(256) void k_lnproj(const float* __restrict__ mm,
                                                const float* __restrict__ gamma,
                                                const float* __restrict__ beta,
                                                const float* __restrict__ b1,
                                                const float* __restrict__ b2,
                                                const __hip_bfloat16* __restrict__ W12bf,
                                                __hip_bfloat16* __restrict__ Ap,
                                                __hip_bfloat16* __restrict__ Bp) {
    __shared__ char sMN[4][8192];      // per-wave [16 rows][256 d] bf16, XOR-swizzled
    const int lane = threadIdx.x & 63;
    const int wid  = threadIdx.x >> 6;
    const int gw   = blockIdx.x * 4 + wid;   // 0..2047
    const int i_   = gw & 255;
    const int sb   = (gw >> 8) * 16;

    float4 g4  = *(const float4*)&gamma[lane * 4];
    float4 be4 = *(const float4*)&beta[lane * 4];
    char* my = sMN[wid];

    #pragma unroll
    for (int rr = 0; rr < 16; rr++) {
        float4 x = *(const float4*)&mm[((size_t)(sb + rr) * 256 + i_) * 256 + lane * 4];
        float s  = x.x + x.y + x.z + x.w;
        float ss = x.x * x.x + x.y * x.y + x.z * x.z + x.w * x.w;
        #pragma unroll
        for (int off = 32; off; off >>= 1) {
            s  += __shfl_xor(s, off);
            ss += __shfl_xor(ss, off);
        }
        float mu  = s * (1.f / 256.f);
        float var = ss * (1.f / 256.f) - mu * mu;
        float rs  = rsqrtf(var + 1e-5f);
        short4v v;
        v.x = f2bf((x.x - mu) * rs * g4.x + be4.x);
        v.y = f2bf((x.y - mu) * rs * g4.y + be4.y);
        v.z = f2bf((x.z - mu) * rs * g4.z + be4.z);
        v.w = f2bf((x.w - mu) * rs * g4.w + be4.w);
        *(short4v*)(my + rr * 512 + ((lane * 8) ^ ((rr & 7) << 4))) = v;
    }
    // wave-local LDS: no __syncthreads needed

    const short* wt12 = (const short*)W12bf;
    const int g = lane >> 4, r16 = lane & 15;

    f32x4 acc[4];
    #pragma unroll
    for (int nf = 0; nf < 4; nf++) {
        int col = nf * 16 + r16;
        float bv = (col < 32) ? b1[col] : b2[col - 32];
        acc[nf] = (f32x4){bv, bv, bv, bv};
    }
    #pragma unroll
    for (int ks = 0; ks < 8; ks++) {
        int L = ks * 64 + g * 16;
        short8 af = *(const short8*)(my + r16 * 512 + (L ^ ((r16 & 7) << 4)));
        #pragma unroll
        for (int nf = 0; nf < 4; nf++) {
            short8 bfv = *(const short8*)&wt12[(nf * 16 + r16) * 256 + ks * 32 + g * 8];
            acc[nf] = __builtin_amdgcn_mfma_f32_16x16x32_bf16(af, bfv, acc[nf], 0, 0, 0);
        }
    }
    #pragma unroll
    for (int nf = 0; nf < 4; nf++) {
        int col = nf * 16 + r16;
        short* Out = (short*)((col < 32) ? Ap : Bp);
        int cr = col & 31;
        short4v v;
        v.x = f2bf(acc[nf][0]); v.y = f2bf(acc[nf][1]);
        v.z = f2bf(acc[nf][2]); v.w = f2bf(acc[nf][3]);
        *(short4v*)&Out[(i_ * 32 + cr) * 128 + sb + g * 4] = v;
    }
}

// ---------------- Kernel 2: O^T = B'.A'^T (swapped MFMA) fused epilogue ----------------
// 512 thr, 8 waves (2 jk x 4 ic of 64x64). Tile: 128 jk-rows x 256 ic-rows.
// acc regs are k-consecutive -> b64 repack into sP[32 p][512 ck'] (32KB),
// two ck-halves; epilogue: each wave owns 16 z (WoutT read once per block).
__global__ __launch_bounds__(512, 4) void k_gemm3(const __hip_bfloat16* __restrict__ Apb,
                                                  const __hip_bfloat16* __restrict__ Bpb,
                                                  const __hip_bfloat16* __restrict__ WoutT,
                                                  const float* __restrict__ bout,
                                                  float* __restrict__ out) {
    __shared__ char sP[32 * 1024];     // [32 p][512 ck'] bf16, key=((L>>7)^p)&7 XOR<<4

    const int t = threadIdx.x, lane = t & 63, wid = t >> 6;
    const int g = lane >> 4, r16 = lane & 15;
    const int wr = wid >> 2, wc = wid & 3;           // wr: jk-half, wc: ic-quarter
    const int bj = blockIdx.x & 63, bi = blockIdx.x >> 6;   // 64 jk-blocks x 32 ic-blocks

    const short* gB = (const short*)Bpb + (size_t)bj * 128 * 128;   // jk rows (A-operand)
    const short* gA = (const short*)Apb + (size_t)bi * 256 * 128;   // ic rows (B-operand)

    f32x4 acc[4][4];
    #pragma unroll
    for (int mf = 0; mf < 4; mf++)
        #pragma unroll
        for (int nf = 0; nf < 4; nf++)
            acc[mf][nf] = (f32x4){0.f, 0.f, 0.f, 0.f};

    for (int ks = 0; ks < 4; ks++) {
        const int kb = ks * 32 + g * 8;
        short8 af[4], bfv[4];
        #pragma unroll
        for (int mf = 0; mf < 4; mf++)
            af[mf] = *(const short8*)&gB[(wr * 64 + mf * 16 + r16) * 128 + kb];
        #pragma unroll
        for (int nf = 0; nf < 4; nf++)
            bfv[nf] = *(const short8*)&gA[(wc * 64 + nf * 16 + r16) * 128 + kb];
        #pragma unroll
        for (int mf = 0; mf < 4; mf++)
            #pragma unroll
            for (int nf = 0; nf < 4; nf++)
                acc[mf][nf] = __builtin_amdgcn_mfma_f32_16x16x32_bf16(af[mf], bfv[nf], acc[mf][nf], 0, 0, 0);
    }

    // epilogue accumulators: z = wid*16 + r16, rows p 0..31 as 2 m-frags
    const int z = wid * 16 + r16;
    float bv = bout[z];
    f32x4 acc2[2];
    acc2[0] = (f32x4){bv, bv, bv, bv};
    acc2[1] = (f32x4){bv, bv, bv, bv};
    const short* wt = (const short*)WoutT;

    #pragma unroll
    for (int hh = 0; hh < 2; hh++) {
        if (hh) __syncthreads();   // wait: everyone done reading sP half 0
        // ---- repack: this wave's nf in {hh, hh+2} -> c_local = r16, k from (mf, g, reg)
        #pragma unroll
        for (int nfq = 0; nfq < 2; nfq++) {
            const int nf = hh + nfq * 2;
            const int i_local = wc * 2 + nfq;            // 0..7
            #pragma unroll
            for (int mf = 0; mf < 4; mf++) {
                const int j_local = wr * 2 + (mf >> 1);  // 0..3
                const int p = i_local * 4 + j_local;     // 0..31
                const int k0 = (mf & 1) * 16 + g * 4;
                const int L = (r16 * 32 + k0) * 2;       // byte within row, 8B aligned
                const int key = (((L >> 7) ^ p) & 7) << 4;
                short4v v;
                v.x = f2bf(acc[mf][nf][0]); v.y = f2bf(acc[mf][nf][1]);
                v.z = f2bf(acc[mf][nf][2]); v.w = f2bf(acc[mf][nf][3]);
                *(short4v*)(sP + p * 1024 + (L ^ key)) = v;
            }
        }
        __syncthreads();
        // ---- epilogue half hh: K-chunk ck' = 0..511 (global ck = hh*512 + ck')
        #pragma unroll 4
        for (int ks = 0; ks < 16; ks++) {
            short8 wf = *(const short8*)&wt[z * 1024 + hh * 512 + ks * 32 + g * 8];
            #pragma unroll
            for (int q = 0; q < 2; q++) {
                const int row = q * 16 + r16;
                const int L = ks * 64 + g * 16;
                const int key = (((L >> 7) ^ row) & 7) << 4;
                short8 pf = *(const short8*)(sP + row * 1024 + (L ^ key));
                acc2[q] = __builtin_amdgcn_mfma_f32_16x16x32_bf16(pf, wf, acc2[q], 0, 0, 0);
            }
        }
    }

    #pragma unroll
    for (int q = 0; q < 2; q++) {
        #pragma unroll
        for (int reg = 0; reg < 4; reg++) {
            const int p = q * 16 + g * 4 + reg;
            const int ig = bi * 8 + (p >> 2), jg = bj * 4 + (p & 3);
            out[((size_t)(ig * 256 + jg)) * 128 + z] = acc2[q][reg] * (1.f / 128.f);
        }
    }
}

extern "C" void kernel_launch(void* const* d_in, const int* in_sizes, int n_in,
                              void* d_out, int out_size, void* d_ws, size_t ws_size,
                              hipStream_t stream) {
    const float* mm    = (const float*)d_in[0];
    const float* gamma = (const float*)d_in[1];
    const float* beta  = (const float*)d_in[2];
    const float* W1    = (const float*)d_in[3];
    const float* b1    = (const float*)d_in[4];
    const float* W2    = (const float*)d_in[5];
    const float* b2    = (const float*)d_in[6];
    const float* Wout  = (const float*)d_in[7];
    const float* bout  = (const float*)d_in[8];

    __hip_bfloat16* Ap    = (__hip_bfloat16*)((char*)d_ws + WS_A);
    __hip_bfloat16* Bp    = (__hip_bfloat16*)((char*)d_ws + WS_B);
    __hip_bfloat16* WoutT = (__hip_bfloat16*)((char*)d_ws + WS_WT);
    __hip_bfloat16* W12bf = (__hip_bfloat16*)((char*)d_ws + WS_W12);
    float* out = (float*)d_out;

    hipLaunchKernelGGL(k_prep, dim3(576), dim3(256), 0, stream, Wout, W1, W2, WoutT, W12bf);
    hipLaunchKernelGGL(k_lnproj, dim3(512), dim3(256), 0, stream,
                       mm, gamma, beta, b1, b2, W12bf, Ap, Bp);
    hipLaunchKernelGGL(k_gemm3, dim3(2048), dim3(512), 0, stream,
                       Ap, Bp, WoutT, bout, out);
}

// Round 4
// 76.966 us; speedup vs baseline: 2.3732x; 1.8468x over previous
//
#include <hip/hip_runtime.h>
#include <hip/hip_bf16.h>

typedef __attribute__((ext_vector_type(8))) short short8;
typedef __attribute__((ext_vector_type(4))) short short4v;
typedef __attribute__((ext_vector_type(4))) float f32x4;

// ws: A' [8192][128] bf16 (2MB) | B' [8192][128] bf16 (2MB) |
//     WoutT [128][1024] bf16 (256KB) | W12bf [64][256] bf16 (32KB)
#define WS_A   0
#define WS_B   (8192 * 128 * 2)
#define WS_WT  (2 * 8192 * 128 * 2)
#define WS_W12 (WS_WT + 128 * 1024 * 2)

static __device__ __forceinline__ short f2bf(float x) {
    __hip_bfloat16 h = __float2bfloat16(x);
    return *reinterpret_cast<short*>(&h);
}

typedef __attribute__((address_space(3))) unsigned int lds_u32;
typedef const __attribute__((address_space(1))) unsigned int glb_u32;
static __device__ __forceinline__ void stage16(const void* g, void* l) {
    __builtin_amdgcn_global_load_lds((glb_u32*)g, (lds_u32*)l, 16, 0, 0);
}

// ---------------- Kernel 0: Wout -> bf16 [z][ck]; W1|W2 -> bf16 [64 c][256 d] ----------------
__global__ __launch_bounds__(256) void k_prep(const float* __restrict__ Wout,
                                              const float* __restrict__ W1,
                                              const float* __restrict__ W2,
                                              __hip_bfloat16* __restrict__ WoutT,
                                              __hip_bfloat16* __restrict__ W12bf) {
    int idx = blockIdx.x * 256 + threadIdx.x;
    if (blockIdx.x < 512) {
        int z = idx >> 10, ck = idx & 1023;
        WoutT[idx] = __float2bfloat16(Wout[ck * 128 + z]);
    } else {
        idx -= 512 * 256;                  // 0..16383
        int c = idx >> 8, d = idx & 255;
        W12bf[idx] = __float2bfloat16(c < 32 ? W1[d * 32 + c] : W2[d * 32 + (c - 32)]);
    }
}

// ---------------- Kernel 1: LayerNorm + dual projection via MFMA (unchanged, verified) --------
__global__ __launch_bounds__(256) void k_lnproj(const float* __restrict__ mm,
                                                const float* __restrict__ gamma,
                                                const float* __restrict__ beta,
                                                const float* __restrict__ b1,
                                                const float* __restrict__ b2,
                                                const __hip_bfloat16* __restrict__ W12bf,
                                                __hip_bfloat16* __restrict__ Ap,
                                                __hip_bfloat16* __restrict__ Bp) {
    __shared__ char sMN[4][8192];      // per-wave [16 rows][256 d] bf16, XOR-swizzled
    const int lane = threadIdx.x & 63;
    const int wid  = threadIdx.x >> 6;
    const int gw   = blockIdx.x * 4 + wid;   // 0..2047
    const int i_   = gw & 255;
    const int sb   = (gw >> 8) * 16;

    float4 g4  = *(const float4*)&gamma[lane * 4];
    float4 be4 = *(const float4*)&beta[lane * 4];
    char* my = sMN[wid];

    #pragma unroll
    for (int rr = 0; rr < 16; rr++) {
        float4 x = *(const float4*)&mm[((size_t)(sb + rr) * 256 + i_) * 256 + lane * 4];
        float s  = x.x + x.y + x.z + x.w;
        float ss = x.x * x.x + x.y * x.y + x.z * x.z + x.w * x.w;
        #pragma unroll
        for (int off = 32; off; off >>= 1) {
            s  += __shfl_xor(s, off);
            ss += __shfl_xor(ss, off);
        }
        float mu  = s * (1.f / 256.f);
        float var = ss * (1.f / 256.f) - mu * mu;
        float rs  = rsqrtf(var + 1e-5f);
        short4v v;
        v.x = f2bf((x.x - mu) * rs * g4.x + be4.x);
        v.y = f2bf((x.y - mu) * rs * g4.y + be4.y);
        v.z = f2bf((x.z - mu) * rs * g4.z + be4.z);
        v.w = f2bf((x.w - mu) * rs * g4.w + be4.w);
        *(short4v*)(my + rr * 512 + ((lane * 8) ^ ((rr & 7) << 4))) = v;
    }

    const short* wt12 = (const short*)W12bf;
    const int g = lane >> 4, r16 = lane & 15;

    f32x4 acc[4];
    #pragma unroll
    for (int nf = 0; nf < 4; nf++) {
        int col = nf * 16 + r16;
        float bv = (col < 32) ? b1[col] : b2[col - 32];
        acc[nf] = (f32x4){bv, bv, bv, bv};
    }
    #pragma unroll
    for (int ks = 0; ks < 8; ks++) {
        int L = ks * 64 + g * 16;
        short8 af = *(const short8*)(my + r16 * 512 + (L ^ ((r16 & 7) << 4)));
        #pragma unroll
        for (int nf = 0; nf < 4; nf++) {
            short8 bfv = *(const short8*)&wt12[(nf * 16 + r16) * 256 + ks * 32 + g * 8];
            acc[nf] = __builtin_amdgcn_mfma_f32_16x16x32_bf16(af, bfv, acc[nf], 0, 0, 0);
        }
    }
    #pragma unroll
    for (int nf = 0; nf < 4; nf++) {
        int col = nf * 16 + r16;
        short* Out = (short*)((col < 32) ? Ap : Bp);
        int cr = col & 31;
        short4v v;
        v.x = f2bf(acc[nf][0]); v.y = f2bf(acc[nf][1]);
        v.z = f2bf(acc[nf][2]); v.w = f2bf(acc[nf][3]);
        *(short4v*)&Out[(i_ * 32 + cr) * 128 + sb + g * 4] = v;
    }
}

// ---------------- Kernel 2: staged O^T GEMM (256x256, K=128 in 2 halves) + fused epilogue ----
// LDS map (128KB dyn): [0,32K) sB kh0 | [32K,64K) sA kh0 | [64K,96K) sB kh1 | [96K,128K) sA kh1
// After main GEMM:     [0,64K) sP h0 | [64K,128K) sP h1   ([64 p][512 ck'] each)
// Staging: global_load_lds w16, linear LDS dest, PRE-SWIZZLED global source (granule ^ row&7).
extern __shared__ char lds[];

__global__ __launch_bounds__(512, 2) void k_gemm4(const __hip_bfloat16* __restrict__ Apb,
                                                  const __hip_bfloat16* __restrict__ Bpb,
                                                  const __hip_bfloat16* __restrict__ WoutT,
                                                  const float* __restrict__ bout,
                                                  float* __restrict__ out) {
    const int t = threadIdx.x, lane = t & 63, wid = t >> 6;
    const int g = lane >> 4, r16 = lane & 15;
    const int wr = wid >> 2, wc = wid & 3;            // wr: jk half (2), wc: ic quarter (4)
    const int bi = blockIdx.x >> 5, bj = blockIdx.x & 31;

    const short* gA = (const short*)Apb + (size_t)bi * 256 * 128;   // ic rows
    const short* gB = (const short*)Bpb + (size_t)bj * 256 * 128;   // jk rows

    // ---- stage both K-halves: 16 x global_load_lds(16B). rows 0..255, 128B LDS rows.
    const int srow8 = lane >> 3;                 // row within the wave's 8-row chunk
    const int sgran = (lane & 7) ^ srow8;        // inverse-swizzled source granule (row&7 == srow8)
    #pragma unroll
    for (int kh = 0; kh < 2; kh++) {
        #pragma unroll
        for (int rd = 0; rd < 4; rd++) {
            const int row = rd * 64 + wid * 8 + srow8;
            stage16(gB + row * 128 + kh * 64 + sgran * 8,
                    lds + kh * 65536 + rd * 8192 + wid * 1024);
            stage16(gA + row * 128 + kh * 64 + sgran * 8,
                    lds + kh * 65536 + 32768 + rd * 8192 + wid * 1024);
        }
    }

    asm volatile("s_waitcnt vmcnt(8)" ::: "memory");   // K-half0 staged (own); barrier => all
    __builtin_amdgcn_s_barrier();

    f32x4 acc[8][4];
    #pragma unroll
    for (int mf = 0; mf < 8; mf++)
        #pragma unroll
        for (int nf = 0; nf < 4; nf++)
            acc[mf][nf] = (f32x4){0.f, 0.f, 0.f, 0.f};

    #pragma unroll
    for (int kh = 0; kh < 2; kh++) {
        if (kh) {
            asm volatile("s_waitcnt vmcnt(0)" ::: "memory");
            __builtin_amdgcn_s_barrier();
        }
        const char* sBb = lds + kh * 65536;
        const char* sAb = lds + kh * 65536 + 32768;
        #pragma unroll
        for (int ksl = 0; ksl < 2; ksl++) {
            short8 af[8], bfv[4];
            #pragma unroll
            for (int mf = 0; mf < 8; mf++) {
                const int row = wr * 128 + mf * 16 + r16;
                af[mf] = *(const short8*)(sBb + row * 128 + (((ksl * 4 + g) ^ (row & 7)) << 4));
            }
            #pragma unroll
            for (int nf = 0; nf < 4; nf++) {
                const int row = wc * 64 + nf * 16 + r16;
                bfv[nf] = *(const short8*)(sAb + row * 128 + (((ksl * 4 + g) ^ (row & 7)) << 4));
            }
            __builtin_amdgcn_s_setprio(1);
            #pragma unroll
            for (int mf = 0; mf < 8; mf++)
                #pragma unroll
                for (int nf = 0; nf < 4; nf++)
                    acc[mf][nf] = __builtin_amdgcn_mfma_f32_16x16x32_bf16(af[mf], bfv[nf], acc[mf][nf], 0, 0, 0);
            __builtin_amdgcn_s_setprio(0);
        }
    }
    __builtin_amdgcn_s_barrier();     // all A/B reads done; sP may overwrite

    // epilogue accumulators: z = wid*16 + r16
    const int z = wid * 16 + r16;
    const float bv = bout[z];
    f32x4 acc2[4];
    #pragma unroll
    for (int pf = 0; pf < 4; pf++) acc2[pf] = (f32x4){bv, bv, bv, bv};
    const short* wt = (const short*)WoutT;

    // ---- repack half h into sP[h]: p = i_loc*8 + j_loc, ck' = r16*32 + (mf&1)*16 + g*4 + reg
    #define REPACK(h)                                                                    \
        {                                                                                \
            char* sPh = lds + (h) * 65536;                                               \
            _Pragma("unroll")                                                            \
            for (int nq = 0; nq < 2; nq++) {                                             \
                const int nf = (h) + nq * 2;                                             \
                const int p = (wc * 2 + nq) * 8 + wr * 4;                                \
                _Pragma("unroll")                                                        \
                for (int mf = 0; mf < 8; mf++) {                                         \
                    const int pp = p + (mf >> 1);                                        \
                    const int L = r16 * 64 + (mf & 1) * 32 + g * 8;                      \
                    short4v v;                                                           \
                    v.x = f2bf(acc[mf][nf][0]); v.y = f2bf(acc[mf][nf][1]);              \
                    v.z = f2bf(acc[mf][nf][2]); v.w = f2bf(acc[mf][nf][3]);              \
                    *(short4v*)(sPh + pp * 1024 + (L ^ ((((L >> 7) ^ pp) & 7) << 4))) = v; \
                }                                                                        \
            }                                                                            \
        }

    #define EPI(h)                                                                       \
        {                                                                                \
            const char* sPh = lds + (h) * 65536;                                         \
            _Pragma("unroll 4")                                                          \
            for (int ks = 0; ks < 16; ks++) {                                            \
                short8 wf = *(const short8*)&wt[z * 1024 + (h) * 512 + ks * 32 + g * 8]; \
                _Pragma("unroll")                                                        \
                for (int pf = 0; pf < 4; pf++) {                                         \
                    const int row = pf * 16 + r16;                                       \
                    const int L = ks * 64 + g * 16;                                      \
                    short8 pv = *(const short8*)(sPh + row * 1024 +                      \
                                                 (L ^ ((((L >> 7) ^ row) & 7) << 4)));   \
                    acc2[pf] = __builtin_amdgcn_mfma_f32_16x16x32_bf16(pv, wf, acc2[pf], 0, 0, 0); \
                }                                                                        \
            }                                                                            \
        }

    REPACK(0)
    asm volatile("s_waitcnt lgkmcnt(0)" ::: "memory");
    __builtin_amdgcn_s_barrier();     // sP h0 visible
    REPACK(1)                          // writes [64K,128K) while h0 is read
    EPI(0)
    asm volatile("s_waitcnt lgkmcnt(0)" ::: "memory");
    __builtin_amdgcn_s_barrier();     // sP h1 visible
    EPI(1)

    #pragma unroll
    for (int pf = 0; pf < 4; pf++) {
        #pragma unroll
        for (int reg = 0; reg < 4; reg++) {
            const int p = pf * 16 + g * 4 + reg;
            const int ig = bi * 8 + (p >> 3), jg = bj * 8 + (p & 7);
            out[((size_t)(ig * 256 + jg)) * 128 + z] = acc2[pf][reg] * (1.f / 128.f);
        }
    }
    #undef REPACK
    #undef EPI
}

extern "C" void kernel_launch(void* const* d_in, const int* in_sizes, int n_in,
                              void* d_out, int out_size, void* d_ws, size_t ws_size,
                              hipStream_t stream) {
    const float* mm    = (const float*)d_in[0];
    const float* gamma = (const float*)d_in[1];
    const float* beta  = (const float*)d_in[2];
    const float* W1    = (const float*)d_in[3];
    const float* b1    = (const float*)d_in[4];
    const float* W2    = (const float*)d_in[5];
    const float* b2    = (const float*)d_in[6];
    const float* Wout  = (const float*)d_in[7];
    const float* bout  = (const float*)d_in[8];

    __hip_bfloat16* Ap    = (__hip_bfloat16*)((char*)d_ws + WS_A);
    __hip_bfloat16* Bp    = (__hip_bfloat16*)((char*)d_ws + WS_B);
    __hip_bfloat16* WoutT = (__hip_bfloat16*)((char*)d_ws + WS_WT);
    __hip_bfloat16* W12bf = (__hip_bfloat16*)((char*)d_ws + WS_W12);
    float* out = (float*)d_out;

    (void)hipFuncSetAttribute(reinterpret_cast<const void*>(k_gemm4),
                              hipFuncAttributeMaxDynamicSharedMemorySize, 131072);

    hipLaunchKernelGGL(k_prep, dim3(576), dim3(256), 0, stream, Wout, W1, W2, WoutT, W12bf);
    hipLaunchKernelGGL(k_lnproj, dim3(512), dim3(256), 0, stream,
                       mm, gamma, beta, b1, b2, W12bf, Ap, Bp);
    hipLaunchKernelGGL(k_gemm4, dim3(1024), dim3(512), 131072, stream,
                       Ap, Bp, WoutT, bout, out);
}